// Round 3
// baseline (476.506 us; speedup 1.0000x reference)
//
#include <hip/hip_runtime.h>
#include <math.h>

#define VOCAB 4096
#define NROWS 65536          // B*L = 4*16384
#define DECAYF 0.99f
#define EPSF 1e-5f

typedef unsigned long long u64;
typedef unsigned int u32;

// ---------------- ws layout (in floats) ----------------
// [0,      16384)  packed embed float4 (-2e0,-2e1,-2e2,e2sum)  (4096*4)
// [16384,  20480)  counts (4096)
// [20480,  32768)  weight sums (4096*3)
// [32768,  32770)  err accumulator (double)
// [32770,  32772)  n accumulator (double)

__global__ __launch_bounds__(256) void prep_kernel(const float* __restrict__ embed,
                                                   float4* __restrict__ pack) {
    #pragma clang fp contract(off)
    int v = blockIdx.x * 256 + threadIdx.x;
    if (v >= VOCAB) return;
    float e0 = embed[v * 3 + 0];
    float e1 = embed[v * 3 + 1];
    float e2 = embed[v * 3 + 2];
    // numpy: sum(embed*embed, axis=1) = (e0^2 + e1^2) + e2^2 (each product rounded)
    float e2s = (e0 * e0 + e1 * e1) + e2 * e2;
    // store -2*e (exact power-of-2 scaling) so scan is 1 mul + 2 fma + 2 add
    pack[v] = make_float4(-2.0f * e0, -2.0f * e1, -2.0f * e2, e2s);
}

// Block = 512 thr (8 waves). Lane owns row (blockIdx*64 + lane); wave w scans
// cands [w*512,(w+1)*512) with lane-rotated coalesced dwordx4 loads from L2.
// Argmin kept as packed u64 key (dist_bits<<32 | cand): exact np.argmin
// tie-break independent of scan order.
__global__ __launch_bounds__(512) void vq_main_kernel(
    const float* __restrict__ feats,
    const float4* __restrict__ pack,
    float* __restrict__ quant_out,
    float* __restrict__ idx_out,
    float* __restrict__ cnt,
    float* __restrict__ wsum,
    double* __restrict__ err_acc) {
    #pragma clang fp contract(off)
    __shared__ u64 mk[8][64];              // 4 KB merge scratch

    const int tid  = threadIdx.x;
    const int wave = __builtin_amdgcn_readfirstlane(tid >> 6);  // force SGPR
    const int lane = tid & 63;
    const int row  = blockIdx.x * 64 + lane;

    const float f0 = feats[row * 3 + 0];
    const float f1 = feats[row * 3 + 1];
    const float f2 = feats[row * 3 + 2];
    const float fs = (f0 * f0 + f1 * f1) + f2 * f2;   // numpy rounding

    // wave-uniform slice base (SGPR); per-lane rotated group offset (VGPR)
    const float4* __restrict__ wslice = pack + wave * 512;
    const u32 wbase = (u32)(wave << 9);

    u64 kbest = ~0ull;

    // prefetch group 0
    u32 pg = (u32)lane & 127u;
    float4 c0 = wslice[pg * 4 + 0];
    float4 c1 = wslice[pg * 4 + 1];
    float4 c2 = wslice[pg * 4 + 2];
    float4 c3 = wslice[pg * 4 + 3];

    for (int g = 0; g < 128; ++g) {
        // issue next group's loads while computing current
        u32 npg = (u32)(g + 1 + lane) & 127u;
        float4 n0, n1, n2, n3;
        if (g < 127) {
            n0 = wslice[npg * 4 + 0];
            n1 = wslice[npg * 4 + 1];
            n2 = wslice[npg * 4 + 2];
            n3 = wslice[npg * 4 + 3];
        }
        const u32 cb = wbase + pg * 4u;    // candidate id base for this group
        {
            float t = fmaf(c0.z, f2, fmaf(c0.y, f1, c0.x * f0));
            float d = (fs + t) + c0.w;     // == (fs - 2*dot) + e2s, ref-exact
            u64 k = ((u64)__float_as_uint(d) << 32) | (u64)(cb + 0u);
            kbest = k < kbest ? k : kbest;
        }
        {
            float t = fmaf(c1.z, f2, fmaf(c1.y, f1, c1.x * f0));
            float d = (fs + t) + c1.w;
            u64 k = ((u64)__float_as_uint(d) << 32) | (u64)(cb + 1u);
            kbest = k < kbest ? k : kbest;
        }
        {
            float t = fmaf(c2.z, f2, fmaf(c2.y, f1, c2.x * f0));
            float d = (fs + t) + c2.w;
            u64 k = ((u64)__float_as_uint(d) << 32) | (u64)(cb + 2u);
            kbest = k < kbest ? k : kbest;
        }
        {
            float t = fmaf(c3.z, f2, fmaf(c3.y, f1, c3.x * f0));
            float d = (fs + t) + c3.w;
            u64 k = ((u64)__float_as_uint(d) << 32) | (u64)(cb + 3u);
            kbest = k < kbest ? k : kbest;
        }
        pg = npg;
        c0 = n0; c1 = n1; c2 = n2; c3 = n3;
    }

    // ---- cross-wave merge: u64 min over the 8 wave-partials per row ----
    if (wave != 0) mk[wave][lane] = kbest;
    __syncthreads();
    if (wave == 0) {
        #pragma unroll
        for (int w = 1; w < 8; ++w) {
            u64 k = mk[w][lane];
            kbest = k < kbest ? k : kbest;
        }
        const u32 cand = (u32)kbest;       // low 32 bits = candidate id

        idx_out[row] = (float)cand;
        const float4 p = pack[cand];       // L2 gather
        const float q0 = -0.5f * p.x;      // exact recovery of e
        const float q1 = -0.5f * p.y;
        const float q2 = -0.5f * p.z;
        quant_out[row * 3 + 0] = q0;
        quant_out[row * 3 + 1] = q1;
        quant_out[row * 3 + 2] = q2;

        const float d0 = q0 - f0, d1 = q1 - f1, d2 = q2 - f2;
        float err = d0 * d0 + d1 * d1 + d2 * d2;
        #pragma unroll
        for (int off = 32; off >= 1; off >>= 1) err += __shfl_xor(err, off);
        if (lane == 0) atomicAdd(err_acc, (double)err);

        atomicAdd(&cnt[cand], 1.0f);
        atomicAdd(&wsum[cand * 3 + 0], f0);
        atomicAdd(&wsum[cand * 3 + 1], f1);
        atomicAdd(&wsum[cand * 3 + 2], f2);
    }
}

__global__ __launch_bounds__(256) void ema_kernel(
    const float* __restrict__ ema_cs,
    const float* __restrict__ ema_w,
    const float* __restrict__ cnt,
    const float* __restrict__ wsum,
    float* __restrict__ ncs_out,
    float* __restrict__ nw_out,
    double* __restrict__ n_acc) {
    int v = blockIdx.x * 256 + threadIdx.x;
    if (v >= VOCAB) return;
    float ncs = DECAYF * ema_cs[v] + (1.0f - DECAYF) * cnt[v];
    ncs_out[v] = ncs;
    nw_out[v * 3 + 0] = DECAYF * ema_w[v * 3 + 0] + (1.0f - DECAYF) * wsum[v * 3 + 0];
    nw_out[v * 3 + 1] = DECAYF * ema_w[v * 3 + 1] + (1.0f - DECAYF) * wsum[v * 3 + 1];
    nw_out[v * 3 + 2] = DECAYF * ema_w[v * 3 + 2] + (1.0f - DECAYF) * wsum[v * 3 + 2];

    float s = ncs;
    #pragma unroll
    for (int off = 32; off >= 1; off >>= 1) s += __shfl_xor(s, off);
    if ((threadIdx.x & 63) == 0) atomicAdd(n_acc, (double)s);
}

__global__ __launch_bounds__(256) void final_kernel(
    const float* __restrict__ ncs,
    const float* __restrict__ nw,
    const double* __restrict__ n_acc,
    const double* __restrict__ err_acc,
    float* __restrict__ embed_out,
    float* __restrict__ loss_out) {
    int v = blockIdx.x * 256 + threadIdx.x;
    if (v >= VOCAB) return;
    const float n = (float)(*n_acc);
    const float cs = (ncs[v] + EPSF) / (n + (float)VOCAB * EPSF) * n;
    const float d0 = nw[v * 3 + 0] / cs;
    const float d1 = nw[v * 3 + 1] / cs;
    const float d2 = nw[v * 3 + 2] / cs;
    const float nrm = fmaxf(sqrtf(d1 * d1 + d2 * d2), EPSF);
    embed_out[v * 3 + 0] = d0;
    embed_out[v * 3 + 1] = d1 / nrm;
    embed_out[v * 3 + 2] = d2 / nrm;
    if (v == 0) {
        loss_out[0] = (float)(1.25 * (*err_acc) / (double)(NROWS * 3));
    }
}

extern "C" void kernel_launch(void* const* d_in, const int* in_sizes, int n_in,
                              void* d_out, int out_size, void* d_ws, size_t ws_size,
                              hipStream_t stream) {
    const float* feats  = (const float*)d_in[0];   // 65536*3
    const float* embed  = (const float*)d_in[1];   // 4096*3
    const float* ema_cs = (const float*)d_in[2];   // 4096
    const float* ema_w  = (const float*)d_in[3];   // 4096*3

    float* out = (float*)d_out;
    float* quant_out = out;                         // 196608
    float* idx_out   = out + 196608;                // 65536
    float* loss_out  = out + 262144;                // 1
    float* embed_out = out + 262145;                // 12288
    float* ncs_out   = out + 274433;                // 4096
    float* nw_out    = out + 278529;                // 12288

    float* ws = (float*)d_ws;
    float4* pack   = (float4*)ws;                   // 16384 floats
    float*  cnt    = ws + 16384;                    // 4096
    float*  wsum   = ws + 20480;                    // 12288
    double* err_ac = (double*)(ws + 32768);
    double* n_ac   = (double*)(ws + 32770);

    // zero accumulators (counts + wsum + err + n): floats [16384, 32772)
    hipMemsetAsync(ws + 16384, 0, (32772 - 16384) * sizeof(float), stream);

    prep_kernel<<<VOCAB / 256, 256, 0, stream>>>(embed, pack);
    vq_main_kernel<<<NROWS / 64, 512, 0, stream>>>(feats, pack,
                                                   quant_out, idx_out, cnt, wsum, err_ac);
    ema_kernel<<<VOCAB / 256, 256, 0, stream>>>(ema_cs, ema_w, cnt, wsum,
                                                ncs_out, nw_out, n_ac);
    final_kernel<<<VOCAB / 256, 256, 0, stream>>>(ncs_out, nw_out, n_ac, err_ac,
                                                  embed_out, loss_out);
}

// Round 4
// 395.242 us; speedup vs baseline: 1.2056x; 1.2056x over previous
//
#include <hip/hip_runtime.h>
#include <math.h>

#define VOCAB 4096
#define NROWS 65536          // B*L = 4*16384
#define DECAYF 0.99f
#define EPSF 1e-5f

typedef unsigned long long u64;
typedef unsigned int u32;

// ---------------- ws layout ----------------
// floats [0,      16384)  packed embed float4 (-2e0,-2e1,-2e2,e2sum)
// floats [16384,  20480)  counts (4096)
// floats [20480,  32768)  weight sums (4096*3)
// floats [32768,  32770)  err accumulator (double)
// floats [32770,  32772)  n accumulator (double)
// bytes  [131088, 655376) row keys: 65536 x u64  (monotone dist | cand)

__global__ __launch_bounds__(256) void prep_kernel(const float* __restrict__ embed,
                                                   float4* __restrict__ pack) {
    #pragma clang fp contract(off)
    int v = blockIdx.x * 256 + threadIdx.x;
    if (v >= VOCAB) return;
    float e0 = embed[v * 3 + 0];
    float e1 = embed[v * 3 + 1];
    float e2 = embed[v * 3 + 2];
    // numpy: sum(embed*embed, axis=1) = (e0^2 + e1^2) + e2^2 (each product rounded)
    float e2s = (e0 * e0 + e1 * e1) + e2 * e2;
    // store -2*e (exact pow2 scaling) so scan is 1 mul + 2 fma + 2 add
    pack[v] = make_float4(-2.0f * e0, -2.0f * e1, -2.0f * e2, e2s);
}

// grid = 1024 blocks = 256 row-blocks x 4 table-quarters. Block stages its
// 1024-candidate quarter in LDS (16 KB). 8 waves; wave w scans 128 cands;
// lane owns 4 rows. Cross-block merge via global u64 atomicMin per row.
__global__ __launch_bounds__(512, 8) void vq_scan_kernel(
    const float* __restrict__ feats,
    const float4* __restrict__ pack,
    u64* __restrict__ keys) {
    #pragma clang fp contract(off)
    __shared__ float4 tab[1024];           // 16 KB; aliased as merge scratch later

    const int tid  = threadIdx.x;
    const int wave = tid >> 6;
    const int lane = tid & 63;
    const int quarter = blockIdx.x & 3;
    const int rblk    = blockIdx.x >> 2;
    const int cbase   = quarter << 10;     // 1024 cands per quarter

    // stage quarter-table: 1024 float4 over 512 threads (coalesced)
    tab[tid]       = pack[cbase + tid];
    tab[tid + 512] = pack[cbase + tid + 512];

    // lane's 4 rows: 48 B contiguous = 3x float4
    const int rbase = rblk * 256 + lane * 4;
    const float4 fa = *(const float4*)(feats + rbase * 3);
    const float4 fb = *(const float4*)(feats + rbase * 3 + 4);
    const float4 fc = *(const float4*)(feats + rbase * 3 + 8);
    float f0[4] = {fa.x, fa.w, fb.z, fc.y};
    float f1[4] = {fa.y, fb.x, fb.w, fc.z};
    float f2[4] = {fa.z, fb.y, fc.x, fc.w};
    float fs[4];
    #pragma unroll
    for (int r = 0; r < 4; ++r)
        fs[r] = (f0[r] * f0[r] + f1[r] * f1[r]) + f2[r] * f2[r];

    __syncthreads();

    float best[4] = {INFINITY, INFINITY, INFINITY, INFINITY};
    int   bj[4]   = {0, 0, 0, 0};
    const int w0 = wave << 7;              // 128-cand slice per wave

    #pragma unroll 4
    for (int j = 0; j < 128; ++j) {
        const float4 p = tab[w0 + j];      // broadcast ds_read_b128
        #pragma unroll
        for (int r = 0; r < 4; ++r) {
            // bit-identical to fmaf(e2,f2,fmaf(e1,f1,e0*f0)); then ref rounding
            float t = fmaf(p.z, f2[r], fmaf(p.y, f1[r], p.x * f0[r]));
            float d = (fs[r] + t) + p.w;   // == (fsum - 2*dot) + e2sum
            if (d < best[r]) { best[r] = d; bj[r] = j; }  // strict <: lowest j
        }
    }

    // pack exact-order keys: monotone(dist) in high 32, global cand in low 32
    u64 key[4];
    #pragma unroll
    for (int r = 0; r < 4; ++r) {
        u32 b = __float_as_uint(best[r]);
        u32 mb = b ^ ((u32)((int)b >> 31) | 0x80000000u);   // total order
        key[r] = ((u64)mb << 32) | (u32)(cbase + w0 + bj[r]);
    }

    __syncthreads();                       // all waves done reading tab
    u64* mk = (u64*)tab;                   // [8][64][4] = 16 KB
    if (wave != 0) {
        #pragma unroll
        for (int r = 0; r < 4; ++r) mk[wave * 256 + lane * 4 + r] = key[r];
    }
    __syncthreads();
    if (wave == 0) {
        for (int w = 1; w < 8; ++w) {
            #pragma unroll
            for (int r = 0; r < 4; ++r) {
                u64 k = mk[w * 256 + lane * 4 + r];
                key[r] = k < key[r] ? k : key[r];
            }
        }
        #pragma unroll
        for (int r = 0; r < 4; ++r)
            atomicMin(&keys[rbase + r], key[r]);
    }
}

// expand winners: idx/quant outputs, e_latent err, counts & weight sums
__global__ __launch_bounds__(256) void expand_kernel(
    const float* __restrict__ feats,
    const float4* __restrict__ pack,
    const u64* __restrict__ keys,
    float* __restrict__ quant_out,
    float* __restrict__ idx_out,
    float* __restrict__ cnt,
    float* __restrict__ wsum,
    double* __restrict__ err_acc) {
    #pragma clang fp contract(off)
    const int row = blockIdx.x * 256 + threadIdx.x;
    const u32 cand = (u32)keys[row];       // low 32 bits = argmin index

    const float f0 = feats[row * 3 + 0];
    const float f1 = feats[row * 3 + 1];
    const float f2 = feats[row * 3 + 2];

    idx_out[row] = (float)cand;
    const float4 p = pack[cand];
    const float q0 = -0.5f * p.x;          // exact recovery of e
    const float q1 = -0.5f * p.y;
    const float q2 = -0.5f * p.z;
    quant_out[row * 3 + 0] = q0;
    quant_out[row * 3 + 1] = q1;
    quant_out[row * 3 + 2] = q2;

    const float d0 = q0 - f0, d1 = q1 - f1, d2 = q2 - f2;
    float err = d0 * d0 + d1 * d1 + d2 * d2;
    #pragma unroll
    for (int off = 32; off >= 1; off >>= 1) err += __shfl_xor(err, off);
    if ((threadIdx.x & 63) == 0) atomicAdd(err_acc, (double)err);

    atomicAdd(&cnt[cand], 1.0f);
    atomicAdd(&wsum[cand * 3 + 0], f0);
    atomicAdd(&wsum[cand * 3 + 1], f1);
    atomicAdd(&wsum[cand * 3 + 2], f2);
}

__global__ __launch_bounds__(256) void ema_kernel(
    const float* __restrict__ ema_cs,
    const float* __restrict__ ema_w,
    const float* __restrict__ cnt,
    const float* __restrict__ wsum,
    float* __restrict__ ncs_out,
    float* __restrict__ nw_out,
    double* __restrict__ n_acc) {
    int v = blockIdx.x * 256 + threadIdx.x;
    if (v >= VOCAB) return;
    float ncs = DECAYF * ema_cs[v] + (1.0f - DECAYF) * cnt[v];
    ncs_out[v] = ncs;
    nw_out[v * 3 + 0] = DECAYF * ema_w[v * 3 + 0] + (1.0f - DECAYF) * wsum[v * 3 + 0];
    nw_out[v * 3 + 1] = DECAYF * ema_w[v * 3 + 1] + (1.0f - DECAYF) * wsum[v * 3 + 1];
    nw_out[v * 3 + 2] = DECAYF * ema_w[v * 3 + 2] + (1.0f - DECAYF) * wsum[v * 3 + 2];

    float s = ncs;
    #pragma unroll
    for (int off = 32; off >= 1; off >>= 1) s += __shfl_xor(s, off);
    if ((threadIdx.x & 63) == 0) atomicAdd(n_acc, (double)s);
}

__global__ __launch_bounds__(256) void final_kernel(
    const float* __restrict__ ncs,
    const float* __restrict__ nw,
    const double* __restrict__ n_acc,
    const double* __restrict__ err_acc,
    float* __restrict__ embed_out,
    float* __restrict__ loss_out) {
    int v = blockIdx.x * 256 + threadIdx.x;
    if (v >= VOCAB) return;
    const float n = (float)(*n_acc);
    const float cs = (ncs[v] + EPSF) / (n + (float)VOCAB * EPSF) * n;
    const float d0 = nw[v * 3 + 0] / cs;
    const float d1 = nw[v * 3 + 1] / cs;
    const float d2 = nw[v * 3 + 2] / cs;
    const float nrm = fmaxf(sqrtf(d1 * d1 + d2 * d2), EPSF);
    embed_out[v * 3 + 0] = d0;
    embed_out[v * 3 + 1] = d1 / nrm;
    embed_out[v * 3 + 2] = d2 / nrm;
    if (v == 0) {
        loss_out[0] = (float)(1.25 * (*err_acc) / (double)(NROWS * 3));
    }
}

extern "C" void kernel_launch(void* const* d_in, const int* in_sizes, int n_in,
                              void* d_out, int out_size, void* d_ws, size_t ws_size,
                              hipStream_t stream) {
    const float* feats  = (const float*)d_in[0];   // 65536*3
    const float* embed  = (const float*)d_in[1];   // 4096*3
    const float* ema_cs = (const float*)d_in[2];   // 4096
    const float* ema_w  = (const float*)d_in[3];   // 4096*3

    float* out = (float*)d_out;
    float* quant_out = out;                         // 196608
    float* idx_out   = out + 196608;                // 65536
    float* loss_out  = out + 262144;                // 1
    float* embed_out = out + 262145;                // 12288
    float* ncs_out   = out + 274433;                // 4096
    float* nw_out    = out + 278529;                // 12288

    float* ws = (float*)d_ws;
    float4* pack   = (float4*)ws;                   // floats [0, 16384)
    float*  cnt    = ws + 16384;                    // 4096
    float*  wsum   = ws + 20480;                    // 12288
    double* err_ac = (double*)(ws + 32768);
    double* n_ac   = (double*)(ws + 32770);
    u64*    keys   = (u64*)(ws + 32772);            // 65536 u64 (8-aligned)

    // zero accumulators; set keys to all-ones (u64 max)
    hipMemsetAsync(ws + 16384, 0, (32772 - 16384) * sizeof(float), stream);
    hipMemsetAsync(keys, 0xFF, (size_t)NROWS * sizeof(u64), stream);

    prep_kernel<<<VOCAB / 256, 256, 0, stream>>>(embed, pack);
    vq_scan_kernel<<<1024, 512, 0, stream>>>(feats, pack, keys);
    expand_kernel<<<NROWS / 256, 256, 0, stream>>>(feats, pack, keys,
                                                   quant_out, idx_out, cnt, wsum, err_ac);
    ema_kernel<<<VOCAB / 256, 256, 0, stream>>>(ema_cs, ema_w, cnt, wsum,
                                                ncs_out, nw_out, n_ac);
    final_kernel<<<VOCAB / 256, 256, 0, stream>>>(ncs_out, nw_out, n_ac, err_ac,
                                                  embed_out, loss_out);
}

// Round 5
// 103.038 us; speedup vs baseline: 4.6246x; 3.8359x over previous
//
#include <hip/hip_runtime.h>
#include <math.h>

#define VOCAB 4096
#define NROWS 65536          // B*L = 4*16384
#define DECAYF 0.99f
#define EPSF 1e-5f
#define NSEG 8               // segment-sum privatization blocks

typedef unsigned long long u64;
typedef unsigned int u32;

// ---------------- ws layout (floats) ----------------
// [0,      16384)   pack float4 (-2e0,-2e1,-2e2,e2sum)
// [16384,  49152)   pcnt[NSEG][4096]
// [49152,  147456)  pw[NSEG][12288]
// [147456, 148480)  errpart: 512 doubles
// [148480, 148482)  n_acc double

__global__ __launch_bounds__(256) void prep_kernel(const float* __restrict__ embed,
                                                   float4* __restrict__ pack) {
    #pragma clang fp contract(off)
    int v = blockIdx.x * 256 + threadIdx.x;
    if (v >= VOCAB) return;
    float e0 = embed[v * 3 + 0];
    float e1 = embed[v * 3 + 1];
    float e2 = embed[v * 3 + 2];
    // numpy: sum(embed*embed, axis=1) = (e0^2 + e1^2) + e2^2 (each product rounded)
    float e2s = (e0 * e0 + e1 * e1) + e2 * e2;
    pack[v] = make_float4(-2.0f * e0, -2.0f * e1, -2.0f * e2, e2s);
}

// grid=512, block=1024 (16 waves). Full 4096-cand table in 64KB LDS; block
// covers 128 rows (lane owns 2); wave w scans cands [w*256,(w+1)*256).
// In-block u64-key merge = exact np.argmin. Wave 0 writes idx/quant + err
// partial. NO global atomics.
__global__ __launch_bounds__(1024, 8) void vq_scan_kernel(
    const float* __restrict__ feats,
    const float4* __restrict__ pack,
    float* __restrict__ quant_out,
    float* __restrict__ idx_out,
    double* __restrict__ errpart) {
    #pragma clang fp contract(off)
    __shared__ float4 tab[4096];           // 64 KB; aliased as merge scratch later

    const int tid  = threadIdx.x;
    const int wave = tid >> 6;
    const int lane = tid & 63;

    // stage full table: 4096 float4 over 1024 threads (coalesced)
    #pragma unroll
    for (int k = 0; k < 4; ++k)
        tab[tid + k * 1024] = pack[tid + k * 1024];

    // lane's 2 rows: 24 B = 3x float2 (8B-aligned since r0 is even)
    const int r0 = blockIdx.x * 128 + lane * 2;
    const float2 g0 = *(const float2*)(feats + r0 * 3);
    const float2 g1 = *(const float2*)(feats + r0 * 3 + 2);
    const float2 g2 = *(const float2*)(feats + r0 * 3 + 4);
    float f0[2] = {g0.x, g1.y};
    float f1[2] = {g0.y, g2.x};
    float f2[2] = {g1.x, g2.y};
    float fs[2];
    #pragma unroll
    for (int r = 0; r < 2; ++r)
        fs[r] = (f0[r] * f0[r] + f1[r] * f1[r]) + f2[r] * f2[r];

    __syncthreads();

    float best[2] = {INFINITY, INFINITY};
    int   bj[2]   = {0, 0};
    const int w0 = wave << 8;              // 256-cand slice per wave

    #pragma unroll 4
    for (int j = 0; j < 256; ++j) {
        const float4 p = tab[w0 + j];      // broadcast ds_read_b128
        #pragma unroll
        for (int r = 0; r < 2; ++r) {
            // bit-identical to fmaf(e2,f2,fmaf(e1,f1,e0*f0)); then ref rounding
            float t = fmaf(p.z, f2[r], fmaf(p.y, f1[r], p.x * f0[r]));
            float d = (fs[r] + t) + p.w;   // == (fsum - 2*dot) + e2sum
            if (d < best[r]) { best[r] = d; bj[r] = j; }  // strict <: lowest j
        }
    }

    // exact-order keys: monotone(dist) high 32, global cand low 32
    u64 key[2];
    #pragma unroll
    for (int r = 0; r < 2; ++r) {
        u32 b = __float_as_uint(best[r]);
        u32 mb = b ^ ((u32)((int)b >> 31) | 0x80000000u);   // total order map
        key[r] = ((u64)mb << 32) | (u32)(w0 + bj[r]);
    }

    __syncthreads();                       // all waves done reading tab
    u64* mk = (u64*)tab;                   // [16][64][2] = 16 KB, aliases tab
    if (wave != 0) {
        mk[(wave * 64 + lane) * 2 + 0] = key[0];
        mk[(wave * 64 + lane) * 2 + 1] = key[1];
    }
    __syncthreads();
    if (wave == 0) {
        for (int w = 1; w < 16; ++w) {
            u64 k0 = mk[(w * 64 + lane) * 2 + 0];
            u64 k1 = mk[(w * 64 + lane) * 2 + 1];
            if (k0 < key[0]) key[0] = k0;
            if (k1 < key[1]) key[1] = k1;
        }
        const int c0 = (int)(u32)key[0];
        const int c1 = (int)(u32)key[1];

        const float4 p0 = pack[c0];        // L2-resident gather
        const float4 p1 = pack[c1];
        const float q00 = -0.5f * p0.x, q01 = -0.5f * p0.y, q02 = -0.5f * p0.z;
        const float q10 = -0.5f * p1.x, q11 = -0.5f * p1.y, q12 = -0.5f * p1.z;

        *(float2*)(idx_out + r0) = make_float2((float)c0, (float)c1);
        *(float2*)(quant_out + r0 * 3)     = make_float2(q00, q01);
        *(float2*)(quant_out + r0 * 3 + 2) = make_float2(q02, q10);
        *(float2*)(quant_out + r0 * 3 + 4) = make_float2(q11, q12);

        float d0 = q00 - f0[0], d1 = q01 - f1[0], d2 = q02 - f2[0];
        float e0 = q10 - f0[1], e1 = q11 - f1[1], e2 = q12 - f2[1];
        float err = (d0 * d0 + d1 * d1 + d2 * d2) + (e0 * e0 + e1 * e1 + e2 * e2);
        #pragma unroll
        for (int off = 32; off >= 1; off >>= 1) err += __shfl_xor(err, off);
        if (lane == 0) errpart[blockIdx.x] = (double)err;
    }
}

// segment sums via LDS privatization: NSEG blocks x 1024 thr, each block
// accumulates 8192 rows into 64KB LDS (ds_add_f32), flushes plain stores.
__global__ __launch_bounds__(1024) void seg_kernel(
    const float* __restrict__ feats,
    const float* __restrict__ idx_f,
    float* __restrict__ pcnt,
    float* __restrict__ pw) {
    __shared__ float lcnt[VOCAB];          // 16 KB
    __shared__ float lw[VOCAB * 3];        // 48 KB
    const int t = threadIdx.x;
    const int b = blockIdx.x;

    #pragma unroll
    for (int i = 0; i < 4; ++i)  lcnt[t + i * 1024] = 0.0f;
    #pragma unroll
    for (int i = 0; i < 12; ++i) lw[t + i * 1024] = 0.0f;
    __syncthreads();

    #pragma unroll
    for (int i = 0; i < 8; ++i) {
        const int row = b * 8192 + i * 1024 + t;
        const int cand = (int)idx_f[row];
        const float f0 = feats[row * 3 + 0];
        const float f1 = feats[row * 3 + 1];
        const float f2 = feats[row * 3 + 2];
        atomicAdd(&lcnt[cand], 1.0f);
        atomicAdd(&lw[cand * 3 + 0], f0);
        atomicAdd(&lw[cand * 3 + 1], f1);
        atomicAdd(&lw[cand * 3 + 2], f2);
    }
    __syncthreads();

    #pragma unroll
    for (int i = 0; i < 4; ++i)  pcnt[b * VOCAB + t + i * 1024] = lcnt[t + i * 1024];
    #pragma unroll
    for (int i = 0; i < 12; ++i) pw[b * VOCAB * 3 + t + i * 1024] = lw[t + i * 1024];
}

__global__ __launch_bounds__(256) void ema_kernel(
    const float* __restrict__ ema_cs,
    const float* __restrict__ ema_w,
    const float* __restrict__ pcnt,
    const float* __restrict__ pw,
    float* __restrict__ ncs_out,
    float* __restrict__ nw_out,
    double* __restrict__ n_acc) {
    int v = blockIdx.x * 256 + threadIdx.x;
    if (v >= VOCAB) return;
    float c = 0.0f, w0 = 0.0f, w1 = 0.0f, w2 = 0.0f;
    for (int b = 0; b < NSEG; ++b) {       // ascending b = ascending row order
        c  += pcnt[b * VOCAB + v];
        w0 += pw[b * VOCAB * 3 + v * 3 + 0];
        w1 += pw[b * VOCAB * 3 + v * 3 + 1];
        w2 += pw[b * VOCAB * 3 + v * 3 + 2];
    }
    float ncs = DECAYF * ema_cs[v] + (1.0f - DECAYF) * c;
    ncs_out[v] = ncs;
    nw_out[v * 3 + 0] = DECAYF * ema_w[v * 3 + 0] + (1.0f - DECAYF) * w0;
    nw_out[v * 3 + 1] = DECAYF * ema_w[v * 3 + 1] + (1.0f - DECAYF) * w1;
    nw_out[v * 3 + 2] = DECAYF * ema_w[v * 3 + 2] + (1.0f - DECAYF) * w2;

    float s = ncs;
    #pragma unroll
    for (int off = 32; off >= 1; off >>= 1) s += __shfl_xor(s, off);
    if ((threadIdx.x & 63) == 0) atomicAdd(n_acc, (double)s);
}

__global__ __launch_bounds__(256) void final_kernel(
    const float* __restrict__ ncs,
    const float* __restrict__ nw,
    const double* __restrict__ n_acc,
    const double* __restrict__ errpart,
    float* __restrict__ embed_out,
    float* __restrict__ loss_out) {
    __shared__ double se[256];
    int v = blockIdx.x * 256 + threadIdx.x;
    if (v < VOCAB) {
        const float n = (float)(*n_acc);
        const float cs = (ncs[v] + EPSF) / (n + (float)VOCAB * EPSF) * n;
        const float d0 = nw[v * 3 + 0] / cs;
        const float d1 = nw[v * 3 + 1] / cs;
        const float d2 = nw[v * 3 + 2] / cs;
        const float nrm = fmaxf(sqrtf(d1 * d1 + d2 * d2), EPSF);
        embed_out[v * 3 + 0] = d0;
        embed_out[v * 3 + 1] = d1 / nrm;
        embed_out[v * 3 + 2] = d2 / nrm;
    }
    if (blockIdx.x == 0) {
        const int t = threadIdx.x;
        se[t] = errpart[t] + errpart[t + 256];
        __syncthreads();
        #pragma unroll
        for (int s = 128; s > 0; s >>= 1) {
            if (t < s) se[t] += se[t + s];
            __syncthreads();
        }
        if (t == 0)
            loss_out[0] = (float)(1.25 * se[0] / (double)(NROWS * 3));
    }
}

extern "C" void kernel_launch(void* const* d_in, const int* in_sizes, int n_in,
                              void* d_out, int out_size, void* d_ws, size_t ws_size,
                              hipStream_t stream) {
    const float* feats  = (const float*)d_in[0];   // 65536*3
    const float* embed  = (const float*)d_in[1];   // 4096*3
    const float* ema_cs = (const float*)d_in[2];   // 4096
    const float* ema_w  = (const float*)d_in[3];   // 4096*3

    float* out = (float*)d_out;
    float* quant_out = out;                         // 196608
    float* idx_out   = out + 196608;                // 65536
    float* loss_out  = out + 262144;                // 1
    float* embed_out = out + 262145;                // 12288
    float* ncs_out   = out + 274433;                // 4096
    float* nw_out    = out + 278529;                // 12288

    float* ws = (float*)d_ws;
    float4* pack    = (float4*)ws;                  // floats [0, 16384)
    float*  pcnt    = ws + 16384;                   // NSEG*4096
    float*  pw      = ws + 49152;                   // NSEG*12288
    double* errpart = (double*)(ws + 147456);       // 512 doubles
    double* n_ac    = (double*)(ws + 148480);       // 1 double

    hipMemsetAsync(n_ac, 0, sizeof(double), stream);

    prep_kernel<<<VOCAB / 256, 256, 0, stream>>>(embed, pack);
    vq_scan_kernel<<<NROWS / 128, 1024, 0, stream>>>(feats, pack,
                                                     quant_out, idx_out, errpart);
    seg_kernel<<<NSEG, 1024, 0, stream>>>(feats, idx_out, pcnt, pw);
    ema_kernel<<<VOCAB / 256, 256, 0, stream>>>(ema_cs, ema_w, pcnt, pw,
                                                ncs_out, nw_out, n_ac);
    final_kernel<<<VOCAB / 256, 256, 0, stream>>>(ncs_out, nw_out, n_ac, errpart,
                                                  embed_out, loss_out);
}